// Round 2
// baseline (274.884 us; speedup 1.0000x reference)
//
#include <hip/hip_runtime.h>
#include <math.h>

// Problem constants (match reference)
#define ALPHA     1.0f
#define BETA      0.001f
#define GAMMA     0.1f
#define THRESH    0.5f
#define LOG_CLAMP -100.0f
#define LN2       0.69314718055994530942f

constexpr int B = 256, C = 2, H = 192, W = 256;
constexpr int HW   = H * W;          // 49152
constexpr int HW4  = HW / 4;         // 12288 float4 per (b,c) slab
constexpr long long NTOT = (long long)B * C * H * W;  // 25165824
constexpr int N4   = (int)(NTOT / 4);                  // 6291456

// Fast log via hardware v_log_f32 (log2), 1-ulp class accuracy.
// Inputs are in (1e-4, 1-1e-4) so no inf/nan; clamp kept for semantics.
__device__ __forceinline__ float fast_log(float x) {
    return fmaxf(__builtin_amdgcn_logf(x) * LN2, LOG_CLAMP);
}

__device__ __forceinline__ float wave_reduce(float v) {
#pragma unroll
    for (int off = 32; off > 0; off >>= 1)
        v += __shfl_down(v, off, 64);
    return v;
}

__global__ void zero_ws(float* ws) {
    ws[0] = 0.0f;  // bce sum
    ws[1] = 0.0f;  // cuts count
    ws[2] = 0.0f;  // dense sum
}

// ---- BCE sum over all elements + channel-0 count(>0.5), float4 vectorized ----
__global__ __launch_bounds__(256) void bce_cuts_kernel(
        const float4* __restrict__ p4,
        const float4* __restrict__ t4,
        float* __restrict__ ws) {
    float bce  = 0.0f;
    float cuts = 0.0f;
    const int stride = gridDim.x * blockDim.x;
    for (int f = blockIdx.x * blockDim.x + threadIdx.x; f < N4; f += stride) {
        float4 p = p4[f];
        float4 t = t4[f];
        int c = (f / HW4) & 1;   // channel of this float4 (HW divisible by 4)

        // t*log(p) + (1-t)*log(1-p), hardware log
        bce += t.x * fast_log(p.x) + (1.0f - t.x) * fast_log(1.0f - p.x);
        bce += t.y * fast_log(p.y) + (1.0f - t.y) * fast_log(1.0f - p.y);
        bce += t.z * fast_log(p.z) + (1.0f - t.z) * fast_log(1.0f - p.z);
        bce += t.w * fast_log(p.w) + (1.0f - t.w) * fast_log(1.0f - p.w);

        if (c == 0) {
            cuts += (p.x > THRESH ? 1.0f : 0.0f)
                  + (p.y > THRESH ? 1.0f : 0.0f)
                  + (p.z > THRESH ? 1.0f : 0.0f)
                  + (p.w > THRESH ? 1.0f : 0.0f);
        }
    }

    __shared__ float sb[4], sc[4];
    float rb = wave_reduce(bce);
    float rc = wave_reduce(cuts);
    const int lane = threadIdx.x & 63;
    const int wid  = threadIdx.x >> 6;
    if (lane == 0) { sb[wid] = rb; sc[wid] = rc; }
    __syncthreads();
    if (threadIdx.x == 0) {
        atomicAdd(&ws[0], sb[0] + sb[1] + sb[2] + sb[3]);
        atomicAdd(&ws[1], sc[0] + sc[1] + sc[2] + sc[3]);
    }
}

// ---- dense penalty: one thread per (b, w) column of channel 1 ----
// Replicates lax.scan over i = 0 .. H-2:
//   m = p > 0.5 ; if (m && prev != 0) acc += 1/(i-prev)^3 ; if (m) prev = i
// v_rcp_f32 instead of IEEE divide (191 divides/thread was the VALU hog).
__global__ __launch_bounds__(256) void dense_kernel(
        const float* __restrict__ in,
        float* __restrict__ ws) {
    const int j = blockIdx.x * blockDim.x + threadIdx.x;  // 0 .. B*W-1
    const int b = j >> 8;       // W == 256
    const int w = j & 255;
    const float* col = in + ((b * 2 + 1) * H) * W + w;  // channel 1 of batch b

    int prev = 0;
    float acc = 0.0f;
#pragma unroll 8
    for (int i = 0; i < H - 1; ++i) {
        const bool m = col[i * W] > THRESH;
        const float d = (float)(i - prev);
        const float add = __builtin_amdgcn_rcpf(d * d * d);  // 1/(d^3), ~1 ulp
        acc += (m && prev != 0) ? add : 0.0f;
        prev = m ? i : prev;
    }

    __shared__ float sd[4];
    float r = wave_reduce(acc);
    const int lane = threadIdx.x & 63;
    const int wid  = threadIdx.x >> 6;
    if (lane == 0) sd[wid] = r;
    __syncthreads();
    if (threadIdx.x == 0)
        atomicAdd(&ws[2], sd[0] + sd[1] + sd[2] + sd[3]);
}

__global__ void finalize_kernel(const float* __restrict__ ws,
                                float* __restrict__ out) {
    const float bce = -ws[0] / (float)NTOT;
    out[0] = ALPHA * bce + BETA * ws[1] + GAMMA * ws[2];
}

extern "C" void kernel_launch(void* const* d_in, const int* in_sizes, int n_in,
                              void* d_out, int out_size, void* d_ws, size_t ws_size,
                              hipStream_t stream) {
    const float* inputs  = (const float*)d_in[0];
    const float* targets = (const float*)d_in[1];
    float* out = (float*)d_out;
    float* ws  = (float*)d_ws;

    zero_ws<<<1, 1, 0, stream>>>(ws);

    // 3072 blocks * 256 threads * 8 float4/thread == 6291456 == N4 exactly
    bce_cuts_kernel<<<3072, 256, 0, stream>>>(
        (const float4*)inputs, (const float4*)targets, ws);

    // B*W = 65536 columns, one thread each
    dense_kernel<<<256, 256, 0, stream>>>(inputs, ws);

    finalize_kernel<<<1, 1, 0, stream>>>(ws, out);
}

// Round 3
// 254.561 us; speedup vs baseline: 1.0798x; 1.0798x over previous
//
#include <hip/hip_runtime.h>
#include <math.h>

// Problem constants (match reference)
#define ALPHA     1.0f
#define BETA      0.001f
#define GAMMA     0.1f
#define THRESH    0.5f
#define LOG_CLAMP -100.0f
#define LN2       0.69314718055994530942f

constexpr int B = 256, C = 2, H = 192, W = 256;
constexpr int HW   = H * W;          // 49152
constexpr int HW4  = HW / 4;         // 12288 float4 per (b,c) slab
constexpr long long NTOT = (long long)B * C * H * W;  // 25165824
constexpr int N4   = (int)(NTOT / 4);                  // 6291456

// Hardware v_log_f32 (log2) * ln2, ~1 ulp — threshold is 6.7e3 absolute.
__device__ __forceinline__ float fast_log(float x) {
    return fmaxf(__builtin_amdgcn_logf(x) * LN2, LOG_CLAMP);
}

__device__ __forceinline__ float wave_reduce(float v) {
#pragma unroll
    for (int off = 32; off > 0; off >>= 1)
        v += __shfl_down(v, off, 64);
    return v;
}

__global__ void zero_ws(float* ws) {
    ws[0] = 0.0f;  // bce sum
    ws[1] = 0.0f;  // cuts count
    ws[2] = 0.0f;  // dense sum
}

// ---- BCE sum + channel-0 count(>0.5) ----
// Each thread: 8 float4-pairs, ALL loads issued before ANY use (16 KB/wave
// in flight) — fixes the latency-bound 2-loads-then-wait pattern of R2.
__global__ __launch_bounds__(256) void bce_cuts_kernel(
        const float4* __restrict__ p4,
        const float4* __restrict__ t4,
        float* __restrict__ ws) {
    // 3072 blocks * 256 thr * 8 = 6291456 == N4 exactly; no bounds checks.
    const int base = blockIdx.x * (256 * 8) + threadIdx.x;

    float4 p[8], t[8];
#pragma unroll
    for (int k = 0; k < 8; ++k) {
        p[k] = p4[base + k * 256];
        t[k] = t4[base + k * 256];
    }

    float bce  = 0.0f;
    float cuts = 0.0f;
#pragma unroll
    for (int k = 0; k < 8; ++k) {
        const int f = base + k * 256;
        const int c = (f / HW4) & 1;   // channel of this float4

        bce += t[k].x * fast_log(p[k].x) + (1.0f - t[k].x) * fast_log(1.0f - p[k].x);
        bce += t[k].y * fast_log(p[k].y) + (1.0f - t[k].y) * fast_log(1.0f - p[k].y);
        bce += t[k].z * fast_log(p[k].z) + (1.0f - t[k].z) * fast_log(1.0f - p[k].z);
        bce += t[k].w * fast_log(p[k].w) + (1.0f - t[k].w) * fast_log(1.0f - p[k].w);

        if (c == 0) {
            cuts += (p[k].x > THRESH ? 1.0f : 0.0f)
                  + (p[k].y > THRESH ? 1.0f : 0.0f)
                  + (p[k].z > THRESH ? 1.0f : 0.0f)
                  + (p[k].w > THRESH ? 1.0f : 0.0f);
        }
    }

    __shared__ float sb[4], sc[4];
    float rb = wave_reduce(bce);
    float rc = wave_reduce(cuts);
    const int lane = threadIdx.x & 63;
    const int wid  = threadIdx.x >> 6;
    if (lane == 0) { sb[wid] = rb; sc[wid] = rc; }
    __syncthreads();
    if (threadIdx.x == 0) {
        atomicAdd(&ws[0], sb[0] + sb[1] + sb[2] + sb[3]);
        atomicAdd(&ws[1], sc[0] + sc[1] + sc[2] + sc[3]);
    }
}

// ---- dense penalty, segmented scan ----
// Reference semantics: hits in rows [1..190] of channel 1; for each pair of
// consecutive hits (i,j), add 1/(j-i)^3.  (Row 0 hits set prev=0 == sentinel
// => no-op; row 191 never scanned.)  This is an associative monoid
// (first, last, sum), so split each column into 4 row-segments handled by
// 4 waves of a block, merged in LDS.  4096 waves (16/CU) vs R2's 1024, and
// each thread prefetches its 48 rows into registers => 48 loads in flight.
__global__ __launch_bounds__(256) void dense_kernel(
        const float* __restrict__ in,
        float* __restrict__ ws) {
    const int lane = threadIdx.x & 63;
    const int seg  = threadIdx.x >> 6;            // 0..3, rows [seg*48, seg*48+48)
    const int j    = blockIdx.x * 64 + lane;      // column id, 0..65535
    const int b    = j >> 8;                      // W == 256
    const int w    = j & 255;
    const float* col = in + ((b * 2 + 1) * H) * W + w;  // channel 1 of batch b
    const int segbase = seg * 48;

    float v[48];
#pragma unroll
    for (int k = 0; k < 48; ++k)
        v[k] = col[(segbase + k) * W];

    int   first = -1, last = -1;
    float sum = 0.0f;
#pragma unroll
    for (int k = 0; k < 48; ++k) {
        const int i = segbase + k;
        const bool m = (v[k] > THRESH) && (i != 0) && (i != 191);
        if (m) {
            if (last >= 0) {
                const float d = (float)(i - last);
                sum += __builtin_amdgcn_rcpf(d * d * d);
            } else {
                first = i;
            }
            last = i;
        }
    }

    __shared__ int   sfirst[256];
    __shared__ int   slast[256];
    __shared__ float ssum[256];
    sfirst[threadIdx.x] = first;
    slast[threadIdx.x]  = last;
    ssum[threadIdx.x]   = sum;
    __syncthreads();

    if (threadIdx.x < 64) {  // wave 0 merges the 4 segments of its column
        int   mlast = -1;
        float msum  = 0.0f;
#pragma unroll
        for (int s = 0; s < 4; ++s) {
            const int idx = s * 64 + threadIdx.x;
            const int f = sfirst[idx];
            if (f >= 0) {
                if (mlast >= 0) {
                    const float d = (float)(f - mlast);
                    msum += __builtin_amdgcn_rcpf(d * d * d);
                }
                msum += ssum[idx];
                mlast = slast[idx];
            }
        }
        float r = wave_reduce(msum);
        if (threadIdx.x == 0)
            atomicAdd(&ws[2], r);
    }
}

__global__ void finalize_kernel(const float* __restrict__ ws,
                                float* __restrict__ out) {
    const float bce = -ws[0] / (float)NTOT;
    out[0] = ALPHA * bce + BETA * ws[1] + GAMMA * ws[2];
}

extern "C" void kernel_launch(void* const* d_in, const int* in_sizes, int n_in,
                              void* d_out, int out_size, void* d_ws, size_t ws_size,
                              hipStream_t stream) {
    const float* inputs  = (const float*)d_in[0];
    const float* targets = (const float*)d_in[1];
    float* out = (float*)d_out;
    float* ws  = (float*)d_ws;

    zero_ws<<<1, 1, 0, stream>>>(ws);

    bce_cuts_kernel<<<3072, 256, 0, stream>>>(
        (const float4*)inputs, (const float4*)targets, ws);

    // 1024 blocks * (64 columns x 4 row-segments)
    dense_kernel<<<1024, 256, 0, stream>>>(inputs, ws);

    finalize_kernel<<<1, 1, 0, stream>>>(ws, out);
}

// Round 4
// 223.856 us; speedup vs baseline: 1.2280x; 1.1372x over previous
//
#include <hip/hip_runtime.h>
#include <math.h>

// Problem constants (match reference)
#define ALPHA     1.0f
#define BETA      0.001f
#define GAMMA     0.1f
#define THRESH    0.5f
#define LOG_CLAMP -100.0f
#define LN2       0.69314718055994530942f

constexpr int B = 256, C = 2, H = 192, W = 256;
constexpr int HW   = H * W;          // 49152
constexpr int HW4  = HW / 4;         // 12288 float4 per (b,c) slab
constexpr long long NTOT = (long long)B * C * H * W;  // 25165824
constexpr int N4   = (int)(NTOT / 4);                  // 6291456

constexpr int BCE_BLOCKS   = 6144;   // x 256 thr x 4 pairs == N4 exactly
constexpr int DENSE_BLOCKS = 1024;

// Hardware v_log_f32 (log2) * ln2, ~1 ulp — threshold is 6.7e3 absolute.
__device__ __forceinline__ float fast_log(float x) {
    return fmaxf(__builtin_amdgcn_logf(x) * LN2, LOG_CLAMP);
}

__device__ __forceinline__ float wave_reduce(float v) {
#pragma unroll
    for (int off = 32; off > 0; off >>= 1)
        v += __shfl_down(v, off, 64);
    return v;
}

// ---- BCE sum + channel-0 count(>0.5) ----
// NO contended atomics: each block writes its (bce, cuts) partial to a
// distinct float2 in d_ws.  R3 evidence: 6144 same-address device atomics
// serialized at ~15 ns each == the whole 93 us kernel duration.
__global__ __launch_bounds__(256) void bce_cuts_kernel(
        const float4* __restrict__ p4,
        const float4* __restrict__ t4,
        float2* __restrict__ part) {
    const int base = blockIdx.x * (256 * 4) + threadIdx.x;

    float4 p[4], t[4];
#pragma unroll
    for (int k = 0; k < 4; ++k) {
        p[k] = p4[base + k * 256];
        t[k] = t4[base + k * 256];
    }

    float bce  = 0.0f;
    float cuts = 0.0f;
#pragma unroll
    for (int k = 0; k < 4; ++k) {
        const int f = base + k * 256;
        const int c = (f / HW4) & 1;   // channel of this float4

        bce += t[k].x * fast_log(p[k].x) + (1.0f - t[k].x) * fast_log(1.0f - p[k].x);
        bce += t[k].y * fast_log(p[k].y) + (1.0f - t[k].y) * fast_log(1.0f - p[k].y);
        bce += t[k].z * fast_log(p[k].z) + (1.0f - t[k].z) * fast_log(1.0f - p[k].z);
        bce += t[k].w * fast_log(p[k].w) + (1.0f - t[k].w) * fast_log(1.0f - p[k].w);

        if (c == 0) {
            cuts += (p[k].x > THRESH ? 1.0f : 0.0f)
                  + (p[k].y > THRESH ? 1.0f : 0.0f)
                  + (p[k].z > THRESH ? 1.0f : 0.0f)
                  + (p[k].w > THRESH ? 1.0f : 0.0f);
        }
    }

    __shared__ float sb[4], sc[4];
    float rb = wave_reduce(bce);
    float rc = wave_reduce(cuts);
    const int lane = threadIdx.x & 63;
    const int wid  = threadIdx.x >> 6;
    if (lane == 0) { sb[wid] = rb; sc[wid] = rc; }
    __syncthreads();
    if (threadIdx.x == 0) {
        part[blockIdx.x] = make_float2(sb[0] + sb[1] + sb[2] + sb[3],
                                       sc[0] + sc[1] + sc[2] + sc[3]);
    }
}

// ---- dense penalty, segmented scan (R3 structure, partials not atomics) ----
// Hits in rows [1..190] of channel 1; consecutive hits (i,j) add 1/(j-i)^3.
// Column split into 4 row-segments (4 waves/block), merged via the
// associative (first, last, sum) monoid in LDS.
__global__ __launch_bounds__(256) void dense_kernel(
        const float* __restrict__ in,
        float* __restrict__ part) {
    const int lane = threadIdx.x & 63;
    const int seg  = threadIdx.x >> 6;            // 0..3, rows [seg*48, seg*48+48)
    const int j    = blockIdx.x * 64 + lane;      // column id, 0..65535
    const int b    = j >> 8;                      // W == 256
    const int w    = j & 255;
    const float* col = in + ((b * 2 + 1) * H) * W + w;  // channel 1 of batch b
    const int segbase = seg * 48;

    float v[48];
#pragma unroll
    for (int k = 0; k < 48; ++k)
        v[k] = col[(segbase + k) * W];

    int   first = -1, last = -1;
    float sum = 0.0f;
#pragma unroll
    for (int k = 0; k < 48; ++k) {
        const int i = segbase + k;
        const bool m = (v[k] > THRESH) && (i != 0) && (i != 191);
        if (m) {
            if (last >= 0) {
                const float d = (float)(i - last);
                sum += __builtin_amdgcn_rcpf(d * d * d);
            } else {
                first = i;
            }
            last = i;
        }
    }

    __shared__ int   sfirst[256];
    __shared__ int   slast[256];
    __shared__ float ssum[256];
    sfirst[threadIdx.x] = first;
    slast[threadIdx.x]  = last;
    ssum[threadIdx.x]   = sum;
    __syncthreads();

    if (threadIdx.x < 64) {  // wave 0 merges the 4 segments of its column
        int   mlast = -1;
        float msum  = 0.0f;
#pragma unroll
        for (int s = 0; s < 4; ++s) {
            const int idx = s * 64 + threadIdx.x;
            const int f = sfirst[idx];
            if (f >= 0) {
                if (mlast >= 0) {
                    const float d = (float)(f - mlast);
                    msum += __builtin_amdgcn_rcpf(d * d * d);
                }
                msum += ssum[idx];
                mlast = slast[idx];
            }
        }
        float r = wave_reduce(msum);
        if (threadIdx.x == 0)
            part[blockIdx.x] = r;
    }
}

// ---- single-block reduction of all partials + final combine ----
__global__ __launch_bounds__(256) void finalize_kernel(
        const float2* __restrict__ part_bce,
        const float* __restrict__ part_dense,
        float* __restrict__ out) {
    float b = 0.0f, c = 0.0f, d = 0.0f;
    for (int i = threadIdx.x; i < BCE_BLOCKS; i += 256) {
        float2 v = part_bce[i];
        b += v.x;
        c += v.y;
    }
    for (int i = threadIdx.x; i < DENSE_BLOCKS; i += 256)
        d += part_dense[i];

    __shared__ float sb[4], sc[4], sd[4];
    float rb = wave_reduce(b);
    float rc = wave_reduce(c);
    float rd = wave_reduce(d);
    const int lane = threadIdx.x & 63;
    const int wid  = threadIdx.x >> 6;
    if (lane == 0) { sb[wid] = rb; sc[wid] = rc; sd[wid] = rd; }
    __syncthreads();
    if (threadIdx.x == 0) {
        const float bce_sum   = sb[0] + sb[1] + sb[2] + sb[3];
        const float cuts_sum  = sc[0] + sc[1] + sc[2] + sc[3];
        const float dense_sum = sd[0] + sd[1] + sd[2] + sd[3];
        const float bce = -bce_sum / (float)NTOT;
        out[0] = ALPHA * bce + BETA * cuts_sum + GAMMA * dense_sum;
    }
}

extern "C" void kernel_launch(void* const* d_in, const int* in_sizes, int n_in,
                              void* d_out, int out_size, void* d_ws, size_t ws_size,
                              hipStream_t stream) {
    const float* inputs  = (const float*)d_in[0];
    const float* targets = (const float*)d_in[1];
    float* out = (float*)d_out;

    // ws layout: [0 .. 6143]  float2 bce partials (6144 blocks)
    //            [12288 .. ]  float  dense partials (1024 blocks)
    float2* part_bce   = (float2*)d_ws;
    float*  part_dense = (float*)d_ws + 2 * BCE_BLOCKS;

    bce_cuts_kernel<<<BCE_BLOCKS, 256, 0, stream>>>(
        (const float4*)inputs, (const float4*)targets, part_bce);

    dense_kernel<<<DENSE_BLOCKS, 256, 0, stream>>>(inputs, part_dense);

    finalize_kernel<<<1, 256, 0, stream>>>(part_bce, part_dense, out);
}

// Round 6
// 211.394 us; speedup vs baseline: 1.3003x; 1.0590x over previous
//
#include <hip/hip_runtime.h>
#include <math.h>

// Problem constants (match reference)
#define ALPHA     1.0f
#define BETA      0.001f
#define GAMMA     0.1f
#define THRESH    0.5f
#define LOG_CLAMP -100.0f
#define LN2       0.69314718055994530942f

constexpr int B = 256, C = 2, H = 192, W = 256;
constexpr int HW   = H * W;          // 49152
constexpr int HW4  = HW / 4;         // 12288 float4 per (b,c) slab
constexpr long long NTOT = (long long)B * C * H * W;  // 25165824
constexpr int N4   = (int)(NTOT / 4);                  // 6291456

constexpr int BCE_BLOCKS   = 2048;   // 8 blocks/CU exact fill (32 waves/CU)
constexpr int PAIRS        = 12;     // 2048*256*12 == N4 exactly
constexpr int DENSE_BLOCKS = 1024;

// Native Clang vector type — __builtin_nontemporal_load rejects HIP's
// float4 class (R5 compile error); this has the same 16 B layout.
typedef float vfloat4 __attribute__((ext_vector_type(4)));

// Hardware v_log_f32 (log2) * ln2, ~1 ulp — threshold is 6.7e3 absolute.
__device__ __forceinline__ float fast_log(float x) {
    return fmaxf(__builtin_amdgcn_logf(x) * LN2, LOG_CLAMP);
}

__device__ __forceinline__ vfloat4 nt_load4(const vfloat4* p) {
    return __builtin_nontemporal_load(p);
}

__device__ __forceinline__ float wave_reduce(float v) {
#pragma unroll
    for (int off = 32; off > 0; off >>= 1)
        v += __shfl_down(v, off, 64);
    return v;
}

// ---- BCE sum + channel-0 count(>0.5) ----
// Persistent exact-fill grid (8 blocks/CU), explicit 1-deep software
// pipeline (prefetch k+1 while computing k), nontemporal loads (no reuse).
// R4 evidence: VGPR=20 -> compiler kept only ~2 loads in flight; occupancy
// 60% from 3 dispatch rounds.  Both fixed here.
__global__ __launch_bounds__(256, 8) void bce_cuts_kernel(
        const vfloat4* __restrict__ p4,
        const vfloat4* __restrict__ t4,
        float2* __restrict__ part) {
    // Block covers PAIRS*256 = 3072 contiguous float4 (48 KB per stream).
    const int base = blockIdx.x * (256 * PAIRS) + threadIdx.x;

    float bce  = 0.0f;
    float cuts = 0.0f;

    vfloat4 pc = nt_load4(&p4[base]);
    vfloat4 tc = nt_load4(&t4[base]);

#pragma unroll
    for (int k = 0; k < PAIRS; ++k) {
        vfloat4 pn, tn;
        if (k + 1 < PAIRS) {
            pn = nt_load4(&p4[base + (k + 1) * 256]);
            tn = nt_load4(&t4[base + (k + 1) * 256]);
        }

        const int f = base + k * 256;
        const int c = (f / HW4) & 1;   // channel of this float4

        // lm + t*(lp - lm)  ==  t*lp + (1-t)*lm
#pragma unroll
        for (int e = 0; e < 4; ++e) {
            const float pv = pc[e];
            const float tv = tc[e];
            const float lp = fast_log(pv);
            const float lm = fast_log(1.0f - pv);
            bce += lm + tv * (lp - lm);
            if (c == 0)
                cuts += (pv > THRESH ? 1.0f : 0.0f);
        }

        pc = pn;
        tc = tn;
    }

    __shared__ float sb[4], sc[4];
    float rb = wave_reduce(bce);
    float rc = wave_reduce(cuts);
    const int lane = threadIdx.x & 63;
    const int wid  = threadIdx.x >> 6;
    if (lane == 0) { sb[wid] = rb; sc[wid] = rc; }
    __syncthreads();
    if (threadIdx.x == 0) {
        part[blockIdx.x] = make_float2(sb[0] + sb[1] + sb[2] + sb[3],
                                       sc[0] + sc[1] + sc[2] + sc[3]);
    }
}

// ---- dense penalty, segmented scan (R4 structure, partials not atomics) ----
// Hits in rows [1..190] of channel 1; consecutive hits (i,j) add 1/(j-i)^3.
// Column split into 4 row-segments (4 waves/block), merged via the
// associative (first, last, sum) monoid in LDS.
__global__ __launch_bounds__(256) void dense_kernel(
        const float* __restrict__ in,
        float* __restrict__ part) {
    const int lane = threadIdx.x & 63;
    const int seg  = threadIdx.x >> 6;            // 0..3, rows [seg*48, seg*48+48)
    const int j    = blockIdx.x * 64 + lane;      // column id, 0..65535
    const int b    = j >> 8;                      // W == 256
    const int w    = j & 255;
    const float* col = in + ((b * 2 + 1) * H) * W + w;  // channel 1 of batch b
    const int segbase = seg * 48;

    float v[48];
#pragma unroll
    for (int k = 0; k < 48; ++k)
        v[k] = col[(segbase + k) * W];

    int   first = -1, last = -1;
    float sum = 0.0f;
#pragma unroll
    for (int k = 0; k < 48; ++k) {
        const int i = segbase + k;
        const bool m = (v[k] > THRESH) && (i != 0) && (i != 191);
        if (m) {
            if (last >= 0) {
                const float d = (float)(i - last);
                sum += __builtin_amdgcn_rcpf(d * d * d);
            } else {
                first = i;
            }
            last = i;
        }
    }

    __shared__ int   sfirst[256];
    __shared__ int   slast[256];
    __shared__ float ssum[256];
    sfirst[threadIdx.x] = first;
    slast[threadIdx.x]  = last;
    ssum[threadIdx.x]   = sum;
    __syncthreads();

    if (threadIdx.x < 64) {  // wave 0 merges the 4 segments of its column
        int   mlast = -1;
        float msum  = 0.0f;
#pragma unroll
        for (int s = 0; s < 4; ++s) {
            const int idx = s * 64 + threadIdx.x;
            const int f = sfirst[idx];
            if (f >= 0) {
                if (mlast >= 0) {
                    const float d = (float)(f - mlast);
                    msum += __builtin_amdgcn_rcpf(d * d * d);
                }
                msum += ssum[idx];
                mlast = slast[idx];
            }
        }
        float r = wave_reduce(msum);
        if (threadIdx.x == 0)
            part[blockIdx.x] = r;
    }
}

// ---- single-block reduction of all partials + final combine ----
__global__ __launch_bounds__(256) void finalize_kernel(
        const float2* __restrict__ part_bce,
        const float* __restrict__ part_dense,
        float* __restrict__ out) {
    float b = 0.0f, c = 0.0f, d = 0.0f;
    for (int i = threadIdx.x; i < BCE_BLOCKS; i += 256) {
        float2 v = part_bce[i];
        b += v.x;
        c += v.y;
    }
    for (int i = threadIdx.x; i < DENSE_BLOCKS; i += 256)
        d += part_dense[i];

    __shared__ float sb[4], sc[4], sd[4];
    float rb = wave_reduce(b);
    float rc = wave_reduce(c);
    float rd = wave_reduce(d);
    const int lane = threadIdx.x & 63;
    const int wid  = threadIdx.x >> 6;
    if (lane == 0) { sb[wid] = rb; sc[wid] = rc; sd[wid] = rd; }
    __syncthreads();
    if (threadIdx.x == 0) {
        const float bce_sum   = sb[0] + sb[1] + sb[2] + sb[3];
        const float cuts_sum  = sc[0] + sc[1] + sc[2] + sc[3];
        const float dense_sum = sd[0] + sd[1] + sd[2] + sd[3];
        const float bce = -bce_sum / (float)NTOT;
        out[0] = ALPHA * bce + BETA * cuts_sum + GAMMA * dense_sum;
    }
}

extern "C" void kernel_launch(void* const* d_in, const int* in_sizes, int n_in,
                              void* d_out, int out_size, void* d_ws, size_t ws_size,
                              hipStream_t stream) {
    const float* inputs  = (const float*)d_in[0];
    const float* targets = (const float*)d_in[1];
    float* out = (float*)d_out;

    // ws layout: [0 .. BCE_BLOCKS)  float2 bce partials
    //            then DENSE_BLOCKS float dense partials
    float2* part_bce   = (float2*)d_ws;
    float*  part_dense = (float*)d_ws + 2 * BCE_BLOCKS;

    bce_cuts_kernel<<<BCE_BLOCKS, 256, 0, stream>>>(
        (const vfloat4*)inputs, (const vfloat4*)targets, part_bce);

    dense_kernel<<<DENSE_BLOCKS, 256, 0, stream>>>(inputs, part_dense);

    finalize_kernel<<<1, 256, 0, stream>>>(part_bce, part_dense, out);
}